// Round 3
// baseline (6464.069 us; speedup 1.0000x reference)
//
#include <hip/hip_runtime.h>

// Problem constants
// B=64, T=512, Lc=16, DW=300, CD=50, NF=100, KS=3, H=256, K=9, CV=100
// x dim = DW+NF = 400 ; gates = 4H = 1024

__device__ __forceinline__ float sigf(float x){ return 1.0f/(1.0f + expf(-x)); }

// ---------------- pack weights ----------------
// Wp[d][j] = {Wih[j][d], Wih[256+j][d], Wih[512+j][d], Wih[768+j][d]}   (d<400, j<256)
// WT[d][j] = {Whh[j][d], Whh[256+j][d], Whh[512+j][d], Whh[768+j][d]}   (d<256, j<256)
__global__ void pack_weights(const float* __restrict__ Wih_f, const float* __restrict__ Wih_b,
                             const float* __restrict__ Whh_f, const float* __restrict__ Whh_b,
                             float4* __restrict__ Wp_f, float4* __restrict__ Wp_b,
                             float4* __restrict__ WT_f, float4* __restrict__ WT_b){
  int stride = gridDim.x*blockDim.x;
  for (int idx = blockIdx.x*blockDim.x + threadIdx.x; idx < 335872; idx += stride){
    if (idx < 204800){
      int i2 = idx; const float* W = Wih_f; float4* P = Wp_f;
      if (i2 >= 102400){ i2 -= 102400; W = Wih_b; P = Wp_b; }
      int d = i2 >> 8, j = i2 & 255;
      P[i2] = make_float4(W[j*400+d], W[(j+256)*400+d], W[(j+512)*400+d], W[(j+768)*400+d]);
    } else {
      int i2 = idx - 204800; const float* W = Whh_f; float4* P = WT_f;
      if (i2 >= 65536){ i2 -= 65536; W = Whh_b; P = WT_b; }
      int d = i2 >> 8, j = i2 & 255;
      P[i2] = make_float4(W[j*256+d], W[(j+256)*256+d], W[(j+512)*256+d], W[(j+768)*256+d]);
    }
  }
}

// ---------------- word-emb linear: x[:, 0:300] ----------------
__global__ __launch_bounds__(256) void embed_kernel(const float* __restrict__ we_in,
      const float* __restrict__ finW, const float* __restrict__ finb, float* __restrict__ x){
  __shared__ float embT[300*16];   // [d][tok]
  int tok0 = blockIdx.x * 16;
  for (int idx = threadIdx.x; idx < 4800; idx += 256){
    int tt = idx / 300, d = idx - tt*300;
    embT[d*16 + tt] = we_in[(size_t)tok0*300 + idx];
  }
  __syncthreads();
  for (int j = threadIdx.x; j < 300; j += 256){
    float bias = finb[j];
    float acc[16];
#pragma unroll
    for (int k2=0;k2<16;k2++) acc[k2]=bias;
    const float* wrow = finW + (size_t)j*300;
    const float4* e4 = (const float4*)embT;
#pragma unroll 4
    for (int d=0; d<300; d++){
      float w = wrow[d];
      float4 a = e4[d*4+0], b2 = e4[d*4+1], c2 = e4[d*4+2], d2 = e4[d*4+3];
      acc[0]+=a.x*w;  acc[1]+=a.y*w;  acc[2]+=a.z*w;  acc[3]+=a.w*w;
      acc[4]+=b2.x*w; acc[5]+=b2.y*w; acc[6]+=b2.z*w; acc[7]+=b2.w*w;
      acc[8]+=c2.x*w; acc[9]+=c2.y*w; acc[10]+=c2.z*w;acc[11]+=c2.w*w;
      acc[12]+=d2.x*w;acc[13]+=d2.y*w;acc[14]+=d2.z*w;acc[15]+=d2.w*w;
    }
#pragma unroll
    for (int k2=0;k2<16;k2++) x[(size_t)(tok0+k2)*400 + j] = acc[k2];
  }
}

// ---------------- char CNN: x[:, 300:400] ----------------
__global__ __launch_bounds__(256) void char_kernel(const int* __restrict__ chars,
      const float* __restrict__ char_emb, const float* __restrict__ convW,
      const float* __restrict__ convb, float* __restrict__ x){
  __shared__ float ce2[8*900];     // [tok][c(50)][w1(18)], w1 = pos+1 (zero padded ends)
  __shared__ int chs[128];
  int tok0 = blockIdx.x * 8;
  int tid = threadIdx.x;
  if (tid < 128) chs[tid] = chars[(size_t)tok0*16 + tid];
  __syncthreads();
  for (int idx = tid; idx < 7200; idx += 256){
    int tok = idx / 900; int r = idx - tok*900;
    int w1 = r / 50; int c = r - w1*50;
    float v = 0.f;
    if (w1 >= 1 && w1 <= 16) v = char_emb[chs[tok*16 + (w1-1)]*50 + c];
    ce2[tok*900 + c*18 + w1] = v;
  }
  __syncthreads();
  for (int p = tid; p < 800; p += 256){
    int tok = p / 100, f = p - tok*100;
    float s[16];
#pragma unroll
    for (int w=0; w<16; w++) s[w] = 0.f;
    const float* cebase = ce2 + tok*900;
    for (int c=0; c<50; c++){
      float cr[18];
#pragma unroll
      for (int i=0;i<18;i++) cr[i] = cebase[c*18+i];
#pragma unroll
      for (int k2=0;k2<3;k2++){
        float wv = convW[(k2*50+c)*100 + f];
#pragma unroll
        for (int w=0;w<16;w++) s[w] += cr[w+k2]*wv;
      }
    }
    float m = s[0];
#pragma unroll
    for (int w=1;w<16;w++) m = fmaxf(m, s[w]);
    m = fmaxf(0.f, m + convb[f]);
    x[(size_t)(tok0+tok)*400 + 300 + f] = m;
  }
}

// ---------------- input-gate GEMM for a time-chunk ----------------
__global__ __launch_bounds__(256) void pre_gemm(const float* __restrict__ x,
     const float4* __restrict__ Wp_f, const float4* __restrict__ Wp_b,
     const float* __restrict__ b_f, const float* __restrict__ b_b,
     const int* __restrict__ lengths,
     float4* __restrict__ pre_f, float4* __restrict__ pre_b,
     int t0, int log2CH){
  int dir = blockIdx.z;
  const float4* Wp = dir ? Wp_b : Wp_f;
  const float* bias = dir ? b_b : b_f;
  float4* pre = dir ? pre_b : pre_f;
  int tok0 = blockIdx.x * 64;
  int j0 = blockIdx.y * 64;
  __shared__ float As[16][68];
  __shared__ float4 Bs[4][16][16];
  __shared__ int rows_s[64];
  int tid = threadIdx.x;
  int tx = tid & 15, ty = tid >> 4;
  if (tid < 64){
    int tok = tok0 + tid;
    int b = tok >> log2CH;
    int trel = tok - (b << log2CH);
    int t = t0 + trel;
    int row;
    if (dir == 0) row = t;
    else { int len = lengths[b]; int pr = len - 1 - t; row = pr < 0 ? 0 : pr; }
    rows_s[tid] = b*512 + row;
  }
  float4 acc[4][4];
#pragma unroll
  for (int s2=0;s2<4;s2++){
    int j = j0 + tx*4 + s2;
    float4 bj = make_float4(bias[j], bias[j+256], bias[j+512], bias[j+768]);
#pragma unroll
    for (int r=0;r<4;r++) acc[r][s2] = bj;
  }
  __syncthreads();
  for (int kt=0; kt<25; ++kt){
    int k0 = kt*16;
    for (int idx = tid; idx < 1024; idx += 256){
      int tt = idx >> 4, kk = idx & 15;
      As[kk][tt] = x[(size_t)rows_s[tt]*400 + k0 + kk];
    }
    for (int idx = tid; idx < 1024; idx += 256){
      int kk = idx >> 6, jj = idx & 63;
      int s2 = jj & 3, txw = jj >> 2;
      Bs[s2][kk][txw] = Wp[(size_t)(k0+kk)*256 + j0 + jj];
    }
    __syncthreads();
#pragma unroll
    for (int kk=0; kk<16; ++kk){
      float a[4];
#pragma unroll
      for (int r=0;r<4;r++) a[r] = As[kk][ty*4+r];
#pragma unroll
      for (int s2=0;s2<4;s2++){
        float4 b4 = Bs[s2][kk][tx];
#pragma unroll
        for (int r=0;r<4;r++){
          acc[r][s2].x += a[r]*b4.x;
          acc[r][s2].y += a[r]*b4.y;
          acc[r][s2].z += a[r]*b4.z;
          acc[r][s2].w += a[r]*b4.w;
        }
      }
    }
    __syncthreads();
  }
#pragma unroll
  for (int r=0;r<4;r++){
    int tok = tok0 + ty*4 + r;
#pragma unroll
    for (int s2=0;s2<4;s2++){
      pre[(size_t)tok*256 + j0 + tx*4 + s2] = acc[r][s2];
    }
  }
}

// ---------------- LSTM scan: 512 thr/WG, weights cached in regs+LDS ----------------
// thread (j = tid&255, half = tid>>8): owns d in [half*128, half*128+128)
//   regs:   d_rel [0, NRD)          (NRD float4 per thread)
//   LDS:    d_rel [NRD, NRD+NLD)    (per-half block for all j)
//   stream: d_rel [NRD+NLD, 128)    (from L2 each step)
#define NRD 48
#define NLD 14
#define DSTR (NRD + NLD)          // 62
#define NSTR (128 - DSTR)         // 66

__global__ __launch_bounds__(512, 2) void lstm_scan(const float4* __restrict__ pre_f,
     const float4* __restrict__ pre_b, const float4* __restrict__ WT_f,
     const float4* __restrict__ WT_b, const int* __restrict__ lengths,
     const float* __restrict__ outW,
     float* __restrict__ logits_f, float* __restrict__ logits_b,
     float* __restrict__ st_h, float* __restrict__ st_c,
     int t0, int CH){
  int dir = blockIdx.x & 1;
  int b = blockIdx.x >> 1;
  int len = lengths[b];
  const float4* pre = (dir ? pre_b : pre_f) + (size_t)b*CH*256;
  const float4* WT = dir ? WT_b : WT_f;
  float* lg = (dir ? logits_b : logits_f) + (size_t)b*512*9;
  __shared__ float h_lds[256];
  __shared__ float4 part[256];
  __shared__ float oWs[2304];
  __shared__ float4 wlds[2][NLD][256];   // 112 KB
  int tid = threadIdx.x;
  int j = tid & 255, half = tid >> 8;
  int d0 = half << 7;
  for (int i = tid; i < 2304; i += 512) oWs[i] = outW[dir*2304 + i];
  // LDS-cached weights: d = hh*128 + NRD + dl
  for (int i = tid; i < 2*NLD*256; i += 512){
    int hh = i / (NLD*256);
    int rr = i - hh*(NLD*256);
    int dl = rr >> 8, jj = rr & 255;
    wlds[hh][dl][jj] = WT[(size_t)(hh*128 + NRD + dl)*256 + jj];
  }
  // register-cached weights
  float4 wreg[NRD];
#pragma unroll
  for (int r=0; r<NRD; ++r) wreg[r] = WT[(size_t)(d0 + r)*256 + j];
  float c = 0.f;
  if (t0 == 0){
    if (tid < 256) h_lds[tid] = 0.f;
  } else {
    if (tid < 256) h_lds[tid] = st_h[(dir*64+b)*256 + tid];
    if (half == 0) c = st_c[(dir*64+b)*256 + j];
  }
  __syncthreads();
  int tend = len < t0+CH ? len : t0+CH;
  const float4* WTs = WT + (size_t)(d0 + DSTR)*256 + j;
  const float* hS = h_lds + d0 + DSTR;
  const float* hR = h_lds + d0;
  const float* hL = h_lds + d0 + NRD;
  for (int t=t0; t<tend; ++t){
    int p = dir ? (len-1-t) : t;
    float4 aa0 = make_float4(0.f,0.f,0.f,0.f);
    float4 aa1 = aa0, aa2 = aa0, aa3 = aa0;
    // streamed portion (loads are h-independent; pipeline under FMA)
#pragma unroll 8
    for (int s=0; s<NSTR; ++s){
      float hv = hS[s];
      float4 w = WTs[(size_t)s*256];
      if ((s&3)==0){ aa0.x+=w.x*hv; aa0.y+=w.y*hv; aa0.z+=w.z*hv; aa0.w+=w.w*hv; }
      else if ((s&3)==1){ aa1.x+=w.x*hv; aa1.y+=w.y*hv; aa1.z+=w.z*hv; aa1.w+=w.w*hv; }
      else if ((s&3)==2){ aa2.x+=w.x*hv; aa2.y+=w.y*hv; aa2.z+=w.z*hv; aa2.w+=w.w*hv; }
      else { aa3.x+=w.x*hv; aa3.y+=w.y*hv; aa3.z+=w.z*hv; aa3.w+=w.w*hv; }
    }
    // register portion
#pragma unroll
    for (int r=0; r<NRD; ++r){
      float hv = hR[r];
      float4 w = wreg[r];
      if ((r&3)==0){ aa0.x+=w.x*hv; aa0.y+=w.y*hv; aa0.z+=w.z*hv; aa0.w+=w.w*hv; }
      else if ((r&3)==1){ aa1.x+=w.x*hv; aa1.y+=w.y*hv; aa1.z+=w.z*hv; aa1.w+=w.w*hv; }
      else if ((r&3)==2){ aa2.x+=w.x*hv; aa2.y+=w.y*hv; aa2.z+=w.z*hv; aa2.w+=w.w*hv; }
      else { aa3.x+=w.x*hv; aa3.y+=w.y*hv; aa3.z+=w.z*hv; aa3.w+=w.w*hv; }
    }
    // LDS portion
#pragma unroll
    for (int l=0; l<NLD; ++l){
      float hv = hL[l];
      float4 w = wlds[half][l][j];
      if ((l&3)==0){ aa0.x+=w.x*hv; aa0.y+=w.y*hv; aa0.z+=w.z*hv; aa0.w+=w.w*hv; }
      else if ((l&3)==1){ aa1.x+=w.x*hv; aa1.y+=w.y*hv; aa1.z+=w.z*hv; aa1.w+=w.w*hv; }
      else if ((l&3)==2){ aa2.x+=w.x*hv; aa2.y+=w.y*hv; aa2.z+=w.z*hv; aa2.w+=w.w*hv; }
      else { aa3.x+=w.x*hv; aa3.y+=w.y*hv; aa3.z+=w.z*hv; aa3.w+=w.w*hv; }
    }
    float4 acc = make_float4(aa0.x+aa1.x+aa2.x+aa3.x, aa0.y+aa1.y+aa2.y+aa3.y,
                             aa0.z+aa1.z+aa2.z+aa3.z, aa0.w+aa1.w+aa2.w+aa3.w);
    __syncthreads();                    // all h_lds reads done
    if (half) part[j] = acc;
    __syncthreads();
    if (!half){
      float4 p0 = pre[(size_t)(t - t0)*256 + j];
      float4 p1 = part[j];
      float gi = acc.x + p1.x + p0.x;
      float gf = acc.y + p1.y + p0.y;
      float gg = acc.z + p1.z + p0.z;
      float go = acc.w + p1.w + p0.w;
      c = sigf(gf)*c + sigf(gi)*tanhf(gg);
      float h = sigf(go)*tanhf(c);
      h_lds[j] = h;
    }
    __syncthreads();                    // h ready
    // logits contribution: k = tid>>6 in [0,8), lane l = tid&63 ; then k=8 by first wave
    {
      int k = tid >> 6, l = tid & 63;
      float s = h_lds[l]*oWs[l*9+k] + h_lds[l+64]*oWs[(l+64)*9+k]
              + h_lds[l+128]*oWs[(l+128)*9+k] + h_lds[l+192]*oWs[(l+192)*9+k];
#pragma unroll
      for (int o=32; o; o>>=1) s += __shfl_down(s, o, 64);
      if (l == 0) lg[p*9 + k] = s;
      if (tid < 64){
        float s8 = h_lds[tid]*oWs[tid*9+8] + h_lds[tid+64]*oWs[(tid+64)*9+8]
                 + h_lds[tid+128]*oWs[(tid+128)*9+8] + h_lds[tid+192]*oWs[(tid+192)*9+8];
#pragma unroll
        for (int o=32; o; o>>=1) s8 += __shfl_down(s8, o, 64);
        if (tid == 0) lg[p*9 + 8] = s8;
      }
    }
  }
  if (tid < 256) st_h[(dir*64+b)*256 + tid] = h_lds[tid];
  if (half == 0) st_c[(dir*64+b)*256 + j] = c;
}

// ---------------- merged CRF forward + Viterbi ----------------
__global__ __launch_bounds__(64) void crf_viterbi_kernel(const float* __restrict__ logits_f,
     const float* __restrict__ logits_b, const float* __restrict__ outb_,
     const int* __restrict__ tags, const int* __restrict__ lengths,
     const float* __restrict__ trans, const float* __restrict__ start_trans,
     const float* __restrict__ end_trans, float* __restrict__ loss_partial,
     float* __restrict__ preds){
  int wid = blockIdx.x;
  int is_crf = wid < 64 ? 1 : 0;
  int b = is_crf ? wid : wid - 64;
  int len = lengths[b];
  int tid = threadIdx.x;
  __shared__ float e_s[4608];
  __shared__ float tr[81];
  __shared__ float alpha[9];
  __shared__ int tg[512];
  __shared__ unsigned char bp[4608];
  const float* lf = logits_f + (size_t)b*4608;
  const float* lb = logits_b + (size_t)b*4608;
  for (int i=tid; i<4608; i+=64){
    int k = i - (i/9)*9;
    e_s[i] = lf[i] + lb[i] + outb_[k];
  }
  for (int i=tid; i<81; i+=64) tr[i] = trans[i];
  if (is_crf){
    for (int i=tid; i<512; i+=64) tg[i] = tags[b*512 + i];
    __syncthreads();
    if (tid < 9) alpha[tid] = start_trans[tid] + e_s[tid];
    __syncthreads();
    for (int t=1; t<len; ++t){
      float nxt = 0.f;
      if (tid < 9){
        float v[9];
#pragma unroll
        for (int j2=0;j2<9;j2++) v[j2] = alpha[j2] + tr[j2*9+tid];
        float m = v[0];
#pragma unroll
        for (int j2=1;j2<9;j2++) m = fmaxf(m, v[j2]);
        float ssum = 0.f;
#pragma unroll
        for (int j2=0;j2<9;j2++) ssum += expf(v[j2]-m);
        nxt = m + logf(ssum) + e_s[t*9+tid];
      }
      __syncthreads();
      if (tid < 9) alpha[tid] = nxt;
      __syncthreads();
    }
    if (tid == 0){
      float m = alpha[0] + end_trans[0];
      for (int k2=1;k2<9;k2++) m = fmaxf(m, alpha[k2]+end_trans[k2]);
      float ssum = 0.f;
      for (int k2=0;k2<9;k2++) ssum += expf(alpha[k2]+end_trans[k2]-m);
      float Z = m + logf(ssum);
      int prev = tg[0];
      float sc = start_trans[prev] + e_s[prev];
      for (int t=1;t<len;++t){
        int cur = tg[t];
        sc += tr[prev*9+cur] + e_s[t*9+cur];
        prev = cur;
      }
      sc += end_trans[prev];
      loss_partial[b] = Z - sc;
    }
  } else {
    __syncthreads();
    if (tid < 9) alpha[tid] = start_trans[tid] + e_s[tid];
    __syncthreads();
    for (int t=1; t<len; ++t){
      float nxt = 0.f; int bj = 0;
      if (tid < 9){
        float m = alpha[0] + tr[tid];
#pragma unroll
        for (int j2=1;j2<9;j2++){
          float v = alpha[j2] + tr[j2*9+tid];
          if (v > m){ m = v; bj = j2; }
        }
        nxt = m + e_s[t*9+tid];
      }
      __syncthreads();
      if (tid < 9){ alpha[tid] = nxt; bp[t*9+tid] = (unsigned char)bj; }
      __syncthreads();
    }
    for (int p2 = len + tid; p2 < 512; p2 += 64) preds[(size_t)b*512 + p2] = 0.f;
    if (tid == 0){
      float m = alpha[0] + end_trans[0]; int last = 0;
      for (int k2=1;k2<9;k2++){
        float v = alpha[k2] + end_trans[k2];
        if (v > m){ m = v; last = k2; }
      }
      int cur = last;
      preds[(size_t)b*512 + (len-1)] = (float)cur;
      for (int p2 = len-2; p2 >= 0; --p2){
        cur = bp[(p2+1)*9 + cur];
        preds[(size_t)b*512 + p2] = (float)cur;
      }
    }
  }
}

// ---------------- loss reduction ----------------
__global__ void loss_sum_kernel(const float* __restrict__ lp, float* __restrict__ out){
  float v = lp[threadIdx.x];
#pragma unroll
  for (int o=32; o; o>>=1) v += __shfl_down(v, o, 64);
  if (threadIdx.x == 0) out[0] = v;
}

extern "C" void kernel_launch(void* const* d_in, const int* in_sizes, int n_in,
                              void* d_out, int out_size, void* d_ws, size_t ws_size,
                              hipStream_t stream) {
  const float* word_embs  = (const float*)d_in[0];
  const int*   chars      = (const int*)  d_in[1];
  const int*   lengths    = (const int*)  d_in[2];
  const int*   tags       = (const int*)  d_in[3];
  const float* fin_W      = (const float*)d_in[4];
  const float* fin_b      = (const float*)d_in[5];
  const float* char_emb   = (const float*)d_in[6];
  const float* conv_W     = (const float*)d_in[7];
  const float* conv_b     = (const float*)d_in[8];
  const float* Wih_f      = (const float*)d_in[9];
  const float* Whh_f      = (const float*)d_in[10];
  const float* b_f        = (const float*)d_in[11];
  const float* Wih_b      = (const float*)d_in[12];
  const float* Whh_b      = (const float*)d_in[13];
  const float* b_b        = (const float*)d_in[14];
  const float* out_W      = (const float*)d_in[15];
  const float* out_b      = (const float*)d_in[16];
  const float* trans      = (const float*)d_in[17];
  const float* start_tr   = (const float*)d_in[18];
  const float* end_tr     = (const float*)d_in[19];

  float* ws = (float*)d_ws;
  // fixed layout (floats); all offsets multiple of 64 -> float4-aligned
  float*  x         = ws;                        // 13,107,200
  float4* Wp_f      = (float4*)(ws + 13107200);  //    409,600 floats
  float4* Wp_b      = (float4*)(ws + 13516800);  //    409,600
  float4* WT_f      = (float4*)(ws + 13926400);  //    262,144
  float4* WT_b      = (float4*)(ws + 14188544);  //    262,144
  float*  logits_f  = ws + 14450688;             //    294,912
  float*  logits_b  = ws + 14745600;             //    294,912
  float*  st_h      = ws + 15040512;             //     32,768
  float*  st_c      = ws + 15073280;             //     32,768
  float*  loss_part = ws + 15106048;             //         64
  const size_t FIXED_F = 15106112;               // floats used so far
  // choose largest time-chunk CH whose pre buffers fit ws_size
  int CH = 16, log2CH = 4;
  {
    const int cands[5]  = {512,256,128,64,32};
    const int lgs[5]    = {9,8,7,6,5};
    for (int i=0;i<5;i++){
      size_t need = (FIXED_F + (size_t)131072*cands[i]) * 4;
      if (need <= ws_size){ CH = cands[i]; log2CH = lgs[i]; break; }
    }
  }
  float4* pre_f = (float4*)(ws + FIXED_F);
  float4* pre_b = pre_f + (size_t)64*CH*256;     // 64*CH*1024 floats each

  float* out = (float*)d_out;

  pack_weights<<<1312, 256, 0, stream>>>(Wih_f, Wih_b, Whh_f, Whh_b, Wp_f, Wp_b, WT_f, WT_b);
  embed_kernel<<<2048, 256, 0, stream>>>(word_embs, fin_W, fin_b, x);
  char_kernel<<<4096, 256, 0, stream>>>(chars, char_emb, conv_W, conv_b, x);

  for (int t0 = 0; t0 < 512; t0 += CH){
    pre_gemm<<<dim3(CH, 4, 2), 256, 0, stream>>>(x, Wp_f, Wp_b, b_f, b_b, lengths,
                                                 pre_f, pre_b, t0, log2CH);
    lstm_scan<<<128, 512, 0, stream>>>(pre_f, pre_b, WT_f, WT_b, lengths, out_W,
                                       logits_f, logits_b, st_h, st_c, t0, CH);
  }

  crf_viterbi_kernel<<<128, 64, 0, stream>>>(logits_f, logits_b, out_b, tags, lengths,
                                             trans, start_tr, end_tr, loss_part, out + 1);
  loss_sum_kernel<<<1, 64, 0, stream>>>(loss_part, out);
}

// Round 4
// 4846.825 us; speedup vs baseline: 1.3337x; 1.3337x over previous
//
#include <hip/hip_runtime.h>

// Problem constants
// B=64, T=512, Lc=16, DW=300, CD=50, NF=100, KS=3, H=256, K=9, CV=100
// x dim = DW+NF = 400 ; gates = 4H = 1024

__device__ __forceinline__ float sigf(float x){ return 1.0f/(1.0f + expf(-x)); }

// ---------------- pack weights ----------------
// Wp[d][j] = {Wih[j][d], Wih[256+j][d], Wih[512+j][d], Wih[768+j][d]}   (d<400, j<256)
// WT[d][j] = {Whh[j][d], Whh[256+j][d], Whh[512+j][d], Whh[768+j][d]}   (d<256, j<256)
__global__ void pack_weights(const float* __restrict__ Wih_f, const float* __restrict__ Wih_b,
                             const float* __restrict__ Whh_f, const float* __restrict__ Whh_b,
                             float4* __restrict__ Wp_f, float4* __restrict__ Wp_b,
                             float4* __restrict__ WT_f, float4* __restrict__ WT_b){
  int stride = gridDim.x*blockDim.x;
  for (int idx = blockIdx.x*blockDim.x + threadIdx.x; idx < 335872; idx += stride){
    if (idx < 204800){
      int i2 = idx; const float* W = Wih_f; float4* P = Wp_f;
      if (i2 >= 102400){ i2 -= 102400; W = Wih_b; P = Wp_b; }
      int d = i2 >> 8, j = i2 & 255;
      P[i2] = make_float4(W[j*400+d], W[(j+256)*400+d], W[(j+512)*400+d], W[(j+768)*400+d]);
    } else {
      int i2 = idx - 204800; const float* W = Whh_f; float4* P = WT_f;
      if (i2 >= 65536){ i2 -= 65536; W = Whh_b; P = WT_b; }
      int d = i2 >> 8, j = i2 & 255;
      P[i2] = make_float4(W[j*256+d], W[(j+256)*256+d], W[(j+512)*256+d], W[(j+768)*256+d]);
    }
  }
}

// ---------------- word-emb linear: x[:, 0:300] ----------------
__global__ __launch_bounds__(256) void embed_kernel(const float* __restrict__ we_in,
      const float* __restrict__ finW, const float* __restrict__ finb, float* __restrict__ x){
  __shared__ float embT[300*16];   // [d][tok]
  int tok0 = blockIdx.x * 16;
  for (int idx = threadIdx.x; idx < 4800; idx += 256){
    int tt = idx / 300, d = idx - tt*300;
    embT[d*16 + tt] = we_in[(size_t)tok0*300 + idx];
  }
  __syncthreads();
  for (int j = threadIdx.x; j < 300; j += 256){
    float bias = finb[j];
    float acc[16];
#pragma unroll
    for (int k2=0;k2<16;k2++) acc[k2]=bias;
    const float* wrow = finW + (size_t)j*300;
    const float4* e4 = (const float4*)embT;
#pragma unroll 4
    for (int d=0; d<300; d++){
      float w = wrow[d];
      float4 a = e4[d*4+0], b2 = e4[d*4+1], c2 = e4[d*4+2], d2 = e4[d*4+3];
      acc[0]+=a.x*w;  acc[1]+=a.y*w;  acc[2]+=a.z*w;  acc[3]+=a.w*w;
      acc[4]+=b2.x*w; acc[5]+=b2.y*w; acc[6]+=b2.z*w; acc[7]+=b2.w*w;
      acc[8]+=c2.x*w; acc[9]+=c2.y*w; acc[10]+=c2.z*w;acc[11]+=c2.w*w;
      acc[12]+=d2.x*w;acc[13]+=d2.y*w;acc[14]+=d2.z*w;acc[15]+=d2.w*w;
    }
#pragma unroll
    for (int k2=0;k2<16;k2++) x[(size_t)(tok0+k2)*400 + j] = acc[k2];
  }
}

// ---------------- char CNN: x[:, 300:400] ----------------
__global__ __launch_bounds__(256) void char_kernel(const int* __restrict__ chars,
      const float* __restrict__ char_emb, const float* __restrict__ convW,
      const float* __restrict__ convb, float* __restrict__ x){
  __shared__ float ce2[8*900];     // [tok][c(50)][w1(18)], w1 = pos+1 (zero padded ends)
  __shared__ int chs[128];
  int tok0 = blockIdx.x * 8;
  int tid = threadIdx.x;
  if (tid < 128) chs[tid] = chars[(size_t)tok0*16 + tid];
  __syncthreads();
  for (int idx = tid; idx < 7200; idx += 256){
    int tok = idx / 900; int r = idx - tok*900;
    int w1 = r / 50; int c = r - w1*50;
    float v = 0.f;
    if (w1 >= 1 && w1 <= 16) v = char_emb[chs[tok*16 + (w1-1)]*50 + c];
    ce2[tok*900 + c*18 + w1] = v;
  }
  __syncthreads();
  for (int p = tid; p < 800; p += 256){
    int tok = p / 100, f = p - tok*100;
    float s[16];
#pragma unroll
    for (int w=0; w<16; w++) s[w] = 0.f;
    const float* cebase = ce2 + tok*900;
    for (int c=0; c<50; c++){
      float cr[18];
#pragma unroll
      for (int i=0;i<18;i++) cr[i] = cebase[c*18+i];
#pragma unroll
      for (int k2=0;k2<3;k2++){
        float wv = convW[(k2*50+c)*100 + f];
#pragma unroll
        for (int w=0;w<16;w++) s[w] += cr[w+k2]*wv;
      }
    }
    float m = s[0];
#pragma unroll
    for (int w=1;w<16;w++) m = fmaxf(m, s[w]);
    m = fmaxf(0.f, m + convb[f]);
    x[(size_t)(tok0+tok)*400 + 300 + f] = m;
  }
}

// ---------------- input-gate GEMM for a time-chunk (reg-double-buffered) ----------------
__global__ __launch_bounds__(256) void pre_gemm(const float* __restrict__ x,
     const float4* __restrict__ Wp_f, const float4* __restrict__ Wp_b,
     const float* __restrict__ b_f, const float* __restrict__ b_b,
     const int* __restrict__ lengths,
     float4* __restrict__ pre_f, float4* __restrict__ pre_b,
     int t0, int log2CH){
  int dir = blockIdx.z;
  const float4* Wp = dir ? Wp_b : Wp_f;
  const float* bias = dir ? b_b : b_f;
  float4* pre = dir ? pre_b : pre_f;
  int tok0 = blockIdx.x * 64;
  int j0 = blockIdx.y * 64;
  __shared__ float As[16][68];        // [kk][tok]
  __shared__ float4 Bs[4][16][16];    // [s2][kk][txw]
  __shared__ int rows_s[64];
  int tid = threadIdx.x;
  int tx = tid & 15, ty = tid >> 4;
  if (tid < 64){
    int tok = tok0 + tid;
    int b = tok >> log2CH;
    int trel = tok - (b << log2CH);
    int t = t0 + trel;
    int row;
    if (dir == 0) row = t;
    else { int len = lengths[b]; int pr = len - 1 - t; row = pr < 0 ? 0 : pr; }
    rows_s[tid] = b*512 + row;
  }
  float4 acc[4][4];
#pragma unroll
  for (int s2=0;s2<4;s2++){
    int j = j0 + tx*4 + s2;
    float4 bj = make_float4(bias[j], bias[j+256], bias[j+512], bias[j+768]);
#pragma unroll
    for (int r=0;r<4;r++) acc[r][s2] = bj;
  }
  __syncthreads();
  // staging thread mapping
  int tokA = tid >> 2, kqA = tid & 3;        // A: one float4 along k
  int jjB = tid & 63,  kbB = tid >> 6;       // B: 4 float4
  float4 aReg; float4 bReg[4];
  {
    aReg = *(const float4*)&x[(size_t)rows_s[tokA]*400 + 0 + kqA*4];
#pragma unroll
    for (int rr=0;rr<4;rr++) bReg[rr] = Wp[(size_t)(0 + kbB + rr*4)*256 + j0 + jjB];
  }
  for (int kt=0; kt<25; ++kt){
    // write staged registers to LDS
    As[kqA*4+0][tokA] = aReg.x;
    As[kqA*4+1][tokA] = aReg.y;
    As[kqA*4+2][tokA] = aReg.z;
    As[kqA*4+3][tokA] = aReg.w;
#pragma unroll
    for (int rr=0;rr<4;rr++) Bs[jjB&3][kbB+rr*4][jjB>>2] = bReg[rr];
    __syncthreads();
    if (kt < 24){
      int k0n = (kt+1)*16;
      aReg = *(const float4*)&x[(size_t)rows_s[tokA]*400 + k0n + kqA*4];
#pragma unroll
      for (int rr=0;rr<4;rr++) bReg[rr] = Wp[(size_t)(k0n + kbB + rr*4)*256 + j0 + jjB];
    }
#pragma unroll
    for (int kk=0; kk<16; ++kk){
      float a[4];
#pragma unroll
      for (int r=0;r<4;r++) a[r] = As[kk][ty*4+r];
#pragma unroll
      for (int s2=0;s2<4;s2++){
        float4 b4 = Bs[s2][kk][tx];
#pragma unroll
        for (int r=0;r<4;r++){
          acc[r][s2].x += a[r]*b4.x;
          acc[r][s2].y += a[r]*b4.y;
          acc[r][s2].z += a[r]*b4.z;
          acc[r][s2].w += a[r]*b4.w;
        }
      }
    }
    __syncthreads();
  }
#pragma unroll
  for (int r=0;r<4;r++){
    int tok = tok0 + ty*4 + r;
#pragma unroll
    for (int s2=0;s2<4;s2++){
      pre[(size_t)tok*256 + j0 + tx*4 + s2] = acc[r][s2];
    }
  }
}

// ---------------- LSTM scan: 1024 thr/WG (round-2 structure) + reg/LDS weight cache ----
// thread (j = tid&255, q = tid>>8) covers rows d = q*64 + r, r in [0,64):
//   r < NRD            : register-cached   (NRD*4 VGPR)
//   NRD <= r < NRD+NLD : LDS-cached        (wlds, 4*NLD*256*16 B)
//   else               : streamed from L2 each step
#define NRD 12
#define NLD 8
#define NSTREAM (64 - NRD - NLD)   // 44

__global__ __launch_bounds__(1024, 1) void lstm_scan(const float4* __restrict__ pre_f,
     const float4* __restrict__ pre_b, const float4* __restrict__ WT_f,
     const float4* __restrict__ WT_b, const int* __restrict__ lengths,
     const float* __restrict__ outW,
     float* __restrict__ logits_f, float* __restrict__ logits_b,
     float* __restrict__ st_h, float* __restrict__ st_c,
     int t0, int CH){
  int dir = blockIdx.x & 1;
  int b = blockIdx.x >> 1;
  int len = lengths[b];
  const float4* pre = (dir ? pre_b : pre_f) + (size_t)b*CH*256;
  const float4* WT = dir ? WT_b : WT_f;
  float* lg = (dir ? logits_b : logits_f) + (size_t)b*512*9;
  __shared__ float h_lds[256];
  __shared__ float4 part[3*256];       // 12 KB
  __shared__ float oWs[2304];          // 9 KB
  __shared__ float4 wlds[4][NLD][256]; // 128 KB
  int tid = threadIdx.x;
  int j = tid & 255, q = tid >> 8;
  for (int i = tid; i < 2304; i += 1024) oWs[i] = outW[dir*2304 + i];
  for (int i = tid; i < 4*NLD*256; i += 1024){
    int qq = i >> 11;                 // / (NLD*256) with NLD=8
    int rr = i & (NLD*256 - 1);
    int dl = rr >> 8, jj = rr & 255;
    wlds[qq][dl][jj] = WT[(size_t)(qq*64 + NRD + dl)*256 + jj];
  }
  const float4* WTq = WT + (size_t)q*64*256;
  float4 wreg[NRD];
#pragma unroll
  for (int r=0; r<NRD; ++r) wreg[r] = WTq[(size_t)r*256 + j];
  float c = 0.f;
  if (t0 == 0){
    if (tid < 256) h_lds[tid] = 0.f;
  } else {
    if (tid < 256) h_lds[tid] = st_h[(dir*64+b)*256 + tid];
    if (q == 0) c = st_c[(dir*64+b)*256 + j];
  }
  __syncthreads();
  int tend = len < t0+CH ? len : t0+CH;
  const float4* WTs = WTq + (size_t)(NRD+NLD)*256 + j;
  const float* hR = h_lds + q*64;
  const float* hL = hR + NRD;
  const float* hS = hR + NRD + NLD;
  for (int t=t0; t<tend; ++t){
    int p = dir ? (len-1-t) : t;
    float4 acc = make_float4(0.f,0.f,0.f,0.f);
    // streamed rows (L2)
#pragma unroll 11
    for (int s=0; s<NSTREAM; ++s){
      float hv = hS[s];
      float4 w = WTs[(size_t)s*256];
      acc.x += w.x*hv; acc.y += w.y*hv; acc.z += w.z*hv; acc.w += w.w*hv;
    }
    // register-cached rows
#pragma unroll
    for (int r=0; r<NRD; ++r){
      float hv = hR[r];
      float4 w = wreg[r];
      acc.x += w.x*hv; acc.y += w.y*hv; acc.z += w.z*hv; acc.w += w.w*hv;
    }
    // LDS-cached rows
#pragma unroll
    for (int l=0; l<NLD; ++l){
      float hv = hL[l];
      float4 w = wlds[q][l][j];
      acc.x += w.x*hv; acc.y += w.y*hv; acc.z += w.z*hv; acc.w += w.w*hv;
    }
    __syncthreads();                    // all h_lds reads done
    if (q) part[(q-1)*256 + j] = acc;
    __syncthreads();
    if (q == 0){
      float4 p0 = pre[(size_t)(t - t0)*256 + j];
      float4 p1 = part[j], p2 = part[256+j], p3 = part[512+j];
      float gi = acc.x + p0.x + p1.x + p2.x + p3.x;
      float gf = acc.y + p0.y + p1.y + p2.y + p3.y;
      float gg = acc.z + p0.z + p1.z + p2.z + p3.z;
      float go = acc.w + p0.w + p1.w + p2.w + p3.w;
      c = sigf(gf)*c + sigf(gi)*tanhf(gg);
      float h = sigf(go)*tanhf(c);
      h_lds[j] = h;
    }
    __syncthreads();                    // h ready
    // logits contribution: 9 tags x 64 lanes
    if (tid < 576){
      int k = tid >> 6, l = tid & 63;
      float s = h_lds[l]*oWs[l*9+k] + h_lds[l+64]*oWs[(l+64)*9+k]
              + h_lds[l+128]*oWs[(l+128)*9+k] + h_lds[l+192]*oWs[(l+192)*9+k];
#pragma unroll
      for (int o=32; o; o>>=1) s += __shfl_down(s, o, 64);
      if (l == 0) lg[p*9 + k] = s;
    }
  }
  if (tid < 256) st_h[(dir*64+b)*256 + tid] = h_lds[tid];
  if (q == 0) st_c[(dir*64+b)*256 + j] = c;
}

// ---------------- merged CRF forward + Viterbi ----------------
__global__ __launch_bounds__(64) void crf_viterbi_kernel(const float* __restrict__ logits_f,
     const float* __restrict__ logits_b, const float* __restrict__ outb_,
     const int* __restrict__ tags, const int* __restrict__ lengths,
     const float* __restrict__ trans, const float* __restrict__ start_trans,
     const float* __restrict__ end_trans, float* __restrict__ loss_partial,
     float* __restrict__ preds){
  int wid = blockIdx.x;
  int is_crf = wid < 64 ? 1 : 0;
  int b = is_crf ? wid : wid - 64;
  int len = lengths[b];
  int tid = threadIdx.x;
  __shared__ float e_s[4608];
  __shared__ float tr[81];
  __shared__ float alpha[9];
  __shared__ int tg[512];
  __shared__ unsigned char bp[4608];
  const float* lf = logits_f + (size_t)b*4608;
  const float* lb = logits_b + (size_t)b*4608;
  for (int i=tid; i<4608; i+=64){
    int k = i - (i/9)*9;
    e_s[i] = lf[i] + lb[i] + outb_[k];
  }
  for (int i=tid; i<81; i+=64) tr[i] = trans[i];
  if (is_crf){
    for (int i=tid; i<512; i+=64) tg[i] = tags[b*512 + i];
    __syncthreads();
    if (tid < 9) alpha[tid] = start_trans[tid] + e_s[tid];
    __syncthreads();
    for (int t=1; t<len; ++t){
      float nxt = 0.f;
      if (tid < 9){
        float v[9];
#pragma unroll
        for (int j2=0;j2<9;j2++) v[j2] = alpha[j2] + tr[j2*9+tid];
        float m = v[0];
#pragma unroll
        for (int j2=1;j2<9;j2++) m = fmaxf(m, v[j2]);
        float ssum = 0.f;
#pragma unroll
        for (int j2=0;j2<9;j2++) ssum += expf(v[j2]-m);
        nxt = m + logf(ssum) + e_s[t*9+tid];
      }
      __syncthreads();
      if (tid < 9) alpha[tid] = nxt;
      __syncthreads();
    }
    if (tid == 0){
      float m = alpha[0] + end_trans[0];
      for (int k2=1;k2<9;k2++) m = fmaxf(m, alpha[k2]+end_trans[k2]);
      float ssum = 0.f;
      for (int k2=0;k2<9;k2++) ssum += expf(alpha[k2]+end_trans[k2]-m);
      float Z = m + logf(ssum);
      int prev = tg[0];
      float sc = start_trans[prev] + e_s[prev];
      for (int t=1;t<len;++t){
        int cur = tg[t];
        sc += tr[prev*9+cur] + e_s[t*9+cur];
        prev = cur;
      }
      sc += end_trans[prev];
      loss_partial[b] = Z - sc;
    }
  } else {
    __syncthreads();
    if (tid < 9) alpha[tid] = start_trans[tid] + e_s[tid];
    __syncthreads();
    for (int t=1; t<len; ++t){
      float nxt = 0.f; int bj = 0;
      if (tid < 9){
        float m = alpha[0] + tr[tid];
#pragma unroll
        for (int j2=1;j2<9;j2++){
          float v = alpha[j2] + tr[j2*9+tid];
          if (v > m){ m = v; bj = j2; }
        }
        nxt = m + e_s[t*9+tid];
      }
      __syncthreads();
      if (tid < 9){ alpha[tid] = nxt; bp[t*9+tid] = (unsigned char)bj; }
      __syncthreads();
    }
    for (int p2 = len + tid; p2 < 512; p2 += 64) preds[(size_t)b*512 + p2] = 0.f;
    if (tid == 0){
      float m = alpha[0] + end_trans[0]; int last = 0;
      for (int k2=1;k2<9;k2++){
        float v = alpha[k2] + end_trans[k2];
        if (v > m){ m = v; last = k2; }
      }
      int cur = last;
      preds[(size_t)b*512 + (len-1)] = (float)cur;
      for (int p2 = len-2; p2 >= 0; --p2){
        cur = bp[(p2+1)*9 + cur];
        preds[(size_t)b*512 + p2] = (float)cur;
      }
    }
  }
}

// ---------------- loss reduction ----------------
__global__ void loss_sum_kernel(const float* __restrict__ lp, float* __restrict__ out){
  float v = lp[threadIdx.x];
#pragma unroll
  for (int o=32; o; o>>=1) v += __shfl_down(v, o, 64);
  if (threadIdx.x == 0) out[0] = v;
}

extern "C" void kernel_launch(void* const* d_in, const int* in_sizes, int n_in,
                              void* d_out, int out_size, void* d_ws, size_t ws_size,
                              hipStream_t stream) {
  const float* word_embs  = (const float*)d_in[0];
  const int*   chars      = (const int*)  d_in[1];
  const int*   lengths    = (const int*)  d_in[2];
  const int*   tags       = (const int*)  d_in[3];
  const float* fin_W      = (const float*)d_in[4];
  const float* fin_b      = (const float*)d_in[5];
  const float* char_emb   = (const float*)d_in[6];
  const float* conv_W     = (const float*)d_in[7];
  const float* conv_b     = (const float*)d_in[8];
  const float* Wih_f      = (const float*)d_in[9];
  const float* Whh_f      = (const float*)d_in[10];
  const float* b_f        = (const float*)d_in[11];
  const float* Wih_b      = (const float*)d_in[12];
  const float* Whh_b      = (const float*)d_in[13];
  const float* b_b        = (const float*)d_in[14];
  const float* out_W      = (const float*)d_in[15];
  const float* out_b      = (const float*)d_in[16];
  const float* trans      = (const float*)d_in[17];
  const float* start_tr   = (const float*)d_in[18];
  const float* end_tr     = (const float*)d_in[19];

  float* ws = (float*)d_ws;
  // fixed layout (floats); all offsets multiple of 64 -> float4-aligned
  float*  x         = ws;                        // 13,107,200
  float4* Wp_f      = (float4*)(ws + 13107200);  //    409,600 floats
  float4* Wp_b      = (float4*)(ws + 13516800);  //    409,600
  float4* WT_f      = (float4*)(ws + 13926400);  //    262,144
  float4* WT_b      = (float4*)(ws + 14188544);  //    262,144
  float*  logits_f  = ws + 14450688;             //    294,912
  float*  logits_b  = ws + 14745600;             //    294,912
  float*  st_h      = ws + 15040512;             //     32,768
  float*  st_c      = ws + 15073280;             //     32,768
  float*  loss_part = ws + 15106048;             //         64
  const size_t FIXED_F = 15106112;               // floats used so far
  // choose largest time-chunk CH whose pre buffers fit ws_size
  int CH = 16, log2CH = 4;
  {
    const int cands[5]  = {512,256,128,64,32};
    const int lgs[5]    = {9,8,7,6,5};
    for (int i=0;i<5;i++){
      size_t need = (FIXED_F + (size_t)131072*cands[i]) * 4;
      if (need <= ws_size){ CH = cands[i]; log2CH = lgs[i]; break; }
    }
  }
  float4* pre_f = (float4*)(ws + FIXED_F);
  float4* pre_b = pre_f + (size_t)64*CH*256;     // 64*CH*1024 floats each

  float* out = (float*)d_out;

  pack_weights<<<1312, 256, 0, stream>>>(Wih_f, Wih_b, Whh_f, Whh_b, Wp_f, Wp_b, WT_f, WT_b);
  embed_kernel<<<2048, 256, 0, stream>>>(word_embs, fin_W, fin_b, x);
  char_kernel<<<4096, 256, 0, stream>>>(chars, char_emb, conv_W, conv_b, x);

  for (int t0 = 0; t0 < 512; t0 += CH){
    pre_gemm<<<dim3(CH, 4, 2), 256, 0, stream>>>(x, Wp_f, Wp_b, b_f, b_b, lengths,
                                                 pre_f, pre_b, t0, log2CH);
    lstm_scan<<<128, 1024, 0, stream>>>(pre_f, pre_b, WT_f, WT_b, lengths, out_W,
                                        logits_f, logits_b, st_h, st_c, t0, CH);
  }

  crf_viterbi_kernel<<<128, 64, 0, stream>>>(logits_f, logits_b, out_b, tags, lengths,
                                             trans, start_tr, end_tr, loss_part, out + 1);
  loss_sum_kernel<<<1, 64, 0, stream>>>(loss_part, out);
}

// Round 5
// 4520.172 us; speedup vs baseline: 1.4300x; 1.0723x over previous
//
#include <hip/hip_runtime.h>

// Problem constants
// B=64, T=512, Lc=16, DW=300, CD=50, NF=100, KS=3, H=256, K=9, CV=100
// x dim = DW+NF = 400 ; gates = 4H = 1024

__device__ __forceinline__ float sigf(float x){ return 1.0f/(1.0f + expf(-x)); }

// ---------------- pack weights ----------------
// Wp[d][j] = {Wih[j][d], Wih[256+j][d], Wih[512+j][d], Wih[768+j][d]}   (d<400, j<256)
// WT[d][j] = {Whh[j][d], Whh[256+j][d], Whh[512+j][d], Whh[768+j][d]}   (d<256, j<256)
// finWT[d*304 + j] = fin_W[j*300 + d]                                   (d<300, j<300)
__global__ void pack_weights(const float* __restrict__ Wih_f, const float* __restrict__ Wih_b,
                             const float* __restrict__ Whh_f, const float* __restrict__ Whh_b,
                             const float* __restrict__ fin_W,
                             float4* __restrict__ Wp_f, float4* __restrict__ Wp_b,
                             float4* __restrict__ WT_f, float4* __restrict__ WT_b,
                             float* __restrict__ finWT){
  int stride = gridDim.x*blockDim.x;
  for (int idx = blockIdx.x*blockDim.x + threadIdx.x; idx < 425872; idx += stride){
    if (idx < 204800){
      int i2 = idx; const float* W = Wih_f; float4* P = Wp_f;
      if (i2 >= 102400){ i2 -= 102400; W = Wih_b; P = Wp_b; }
      int d = i2 >> 8, j = i2 & 255;
      P[i2] = make_float4(W[j*400+d], W[(j+256)*400+d], W[(j+512)*400+d], W[(j+768)*400+d]);
    } else if (idx < 335872){
      int i2 = idx - 204800; const float* W = Whh_f; float4* P = WT_f;
      if (i2 >= 65536){ i2 -= 65536; W = Whh_b; P = WT_b; }
      int d = i2 >> 8, j = i2 & 255;
      P[i2] = make_float4(W[j*256+d], W[(j+256)*256+d], W[(j+512)*256+d], W[(j+768)*256+d]);
    } else {
      int i2 = idx - 335872;
      int d = i2 / 300, j = i2 - d*300;
      finWT[d*304 + j] = fin_W[j*300 + d];
    }
  }
}

// ---------------- word-emb linear: x[:, 0:300] (coalesced finWT reads) ----------------
__global__ __launch_bounds__(256) void embed_kernel(const float* __restrict__ we_in,
      const float* __restrict__ finWT, const float* __restrict__ finb, float* __restrict__ x){
  __shared__ float embT[300*16];   // [d][tok]
  int tok0 = blockIdx.x * 16;
  for (int idx = threadIdx.x; idx < 4800; idx += 256){
    int tt = idx / 300, d = idx - tt*300;
    embT[d*16 + tt] = we_in[(size_t)tok0*300 + idx];
  }
  __syncthreads();
  for (int j = threadIdx.x; j < 300; j += 256){
    float bias = finb[j];
    float acc[16];
#pragma unroll
    for (int k2=0;k2<16;k2++) acc[k2]=bias;
    const float4* e4 = (const float4*)embT;
#pragma unroll 4
    for (int d=0; d<300; d++){
      float w = finWT[d*304 + j];
      float4 a = e4[d*4+0], b2 = e4[d*4+1], c2 = e4[d*4+2], d2 = e4[d*4+3];
      acc[0]+=a.x*w;  acc[1]+=a.y*w;  acc[2]+=a.z*w;  acc[3]+=a.w*w;
      acc[4]+=b2.x*w; acc[5]+=b2.y*w; acc[6]+=b2.z*w; acc[7]+=b2.w*w;
      acc[8]+=c2.x*w; acc[9]+=c2.y*w; acc[10]+=c2.z*w;acc[11]+=c2.w*w;
      acc[12]+=d2.x*w;acc[13]+=d2.y*w;acc[14]+=d2.z*w;acc[15]+=d2.w*w;
    }
#pragma unroll
    for (int k2=0;k2<16;k2++) x[(size_t)(tok0+k2)*400 + j] = acc[k2];
  }
}

// ---------------- char CNN: x[:, 300:400] ----------------
__global__ __launch_bounds__(256) void char_kernel(const int* __restrict__ chars,
      const float* __restrict__ char_emb, const float* __restrict__ convW,
      const float* __restrict__ convb, float* __restrict__ x){
  __shared__ float ce2[8*952];     // [tok][c(50)][w1(19 stride)], gcd(19,32)=1 -> bank-clean
  __shared__ int chs[128];
  int tok0 = blockIdx.x * 8;
  int tid = threadIdx.x;
  if (tid < 128) chs[tid] = chars[(size_t)tok0*16 + tid];
  __syncthreads();
  for (int idx = tid; idx < 7200; idx += 256){
    int tok = idx / 900; int r = idx - tok*900;
    int w1 = r / 50; int c = r - w1*50;
    float v = 0.f;
    if (w1 >= 1 && w1 <= 16) v = char_emb[chs[tok*16 + (w1-1)]*50 + c];
    ce2[tok*952 + c*19 + w1] = v;
  }
  __syncthreads();
  for (int p = tid; p < 800; p += 256){
    int tok = p / 100, f = p - tok*100;
    float s[16];
#pragma unroll
    for (int w=0; w<16; w++) s[w] = 0.f;
    const float* cebase = ce2 + tok*952;
    for (int c=0; c<50; c++){
      float cr[18];
#pragma unroll
      for (int i=0;i<18;i++) cr[i] = cebase[c*19+i];
#pragma unroll
      for (int k2=0;k2<3;k2++){
        float wv = convW[(k2*50+c)*100 + f];
#pragma unroll
        for (int w=0;w<16;w++) s[w] += cr[w+k2]*wv;
      }
    }
    float m = s[0];
#pragma unroll
    for (int w=1;w<16;w++) m = fmaxf(m, s[w]);
    m = fmaxf(0.f, m + convb[f]);
    x[(size_t)(tok0+tok)*400 + 300 + f] = m;
  }
}

// ---------------- input-gate GEMM for a time-chunk (reg-double-buffered) ----------------
__global__ __launch_bounds__(256) void pre_gemm(const float* __restrict__ x,
     const float4* __restrict__ Wp_f, const float4* __restrict__ Wp_b,
     const float* __restrict__ b_f, const float* __restrict__ b_b,
     const int* __restrict__ lengths,
     float4* __restrict__ pre_f, float4* __restrict__ pre_b,
     int t0, int log2CH){
  int dir = blockIdx.z;
  const float4* Wp = dir ? Wp_b : Wp_f;
  const float* bias = dir ? b_b : b_f;
  float4* pre = dir ? pre_b : pre_f;
  int tok0 = blockIdx.x * 64;
  int j0 = blockIdx.y * 64;
  __shared__ float As[16][68];        // [kk][tok]
  __shared__ float4 Bs[4][16][16];    // [s2][kk][txw]
  __shared__ int rows_s[64];
  int tid = threadIdx.x;
  int tx = tid & 15, ty = tid >> 4;
  if (tid < 64){
    int tok = tok0 + tid;
    int b = tok >> log2CH;
    int trel = tok - (b << log2CH);
    int t = t0 + trel;
    int row;
    if (dir == 0) row = t;
    else { int len = lengths[b]; int pr = len - 1 - t; row = pr < 0 ? 0 : pr; }
    rows_s[tid] = b*512 + row;
  }
  float4 acc[4][4];
#pragma unroll
  for (int s2=0;s2<4;s2++){
    int j = j0 + tx*4 + s2;
    float4 bj = make_float4(bias[j], bias[j+256], bias[j+512], bias[j+768]);
#pragma unroll
    for (int r=0;r<4;r++) acc[r][s2] = bj;
  }
  __syncthreads();
  // staging thread mapping
  int tokA = tid >> 2, kqA = tid & 3;        // A: one float4 along k
  int jjB = tid & 63,  kbB = tid >> 6;       // B: 4 float4
  float4 aReg; float4 bReg[4];
  {
    aReg = *(const float4*)&x[(size_t)rows_s[tokA]*400 + 0 + kqA*4];
#pragma unroll
    for (int rr=0;rr<4;rr++) bReg[rr] = Wp[(size_t)(0 + kbB + rr*4)*256 + j0 + jjB];
  }
  for (int kt=0; kt<25; ++kt){
    As[kqA*4+0][tokA] = aReg.x;
    As[kqA*4+1][tokA] = aReg.y;
    As[kqA*4+2][tokA] = aReg.z;
    As[kqA*4+3][tokA] = aReg.w;
#pragma unroll
    for (int rr=0;rr<4;rr++) Bs[jjB&3][kbB+rr*4][jjB>>2] = bReg[rr];
    __syncthreads();
    if (kt < 24){
      int k0n = (kt+1)*16;
      aReg = *(const float4*)&x[(size_t)rows_s[tokA]*400 + k0n + kqA*4];
#pragma unroll
      for (int rr=0;rr<4;rr++) bReg[rr] = Wp[(size_t)(k0n + kbB + rr*4)*256 + j0 + jjB];
    }
#pragma unroll
    for (int kk=0; kk<16; ++kk){
      float a[4];
#pragma unroll
      for (int r=0;r<4;r++) a[r] = As[kk][ty*4+r];
#pragma unroll
      for (int s2=0;s2<4;s2++){
        float4 b4 = Bs[s2][kk][tx];
#pragma unroll
        for (int r=0;r<4;r++){
          acc[r][s2].x += a[r]*b4.x;
          acc[r][s2].y += a[r]*b4.y;
          acc[r][s2].z += a[r]*b4.z;
          acc[r][s2].w += a[r]*b4.w;
        }
      }
    }
    __syncthreads();
  }
#pragma unroll
  for (int r=0;r<4;r++){
    int tok = tok0 + ty*4 + r;
#pragma unroll
    for (int s2=0;s2<4;s2++){
      pre[(size_t)tok*256 + j0 + tx*4 + s2] = acc[r][s2];
    }
  }
}

// ---------------- LSTM scan: 1024 thr/WG, NRD=24 reg rows + NLD=8 LDS rows ----
// thread (j = tid&255, q = tid>>8) covers rows d = q*64 + r, r in [0,64):
//   r < NRD            : register-cached   (NRD*4 = 96 VGPR)
//   NRD <= r < NRD+NLD : LDS-cached        (128 KB)
//   else               : streamed from L2 each step (32 rows -> 512 KB/step/WG)
#define NRD 24
#define NLD 8
#define NSTREAM (64 - NRD - NLD)   // 32

__global__ __launch_bounds__(1024, 1) void lstm_scan(const float4* __restrict__ pre_f,
     const float4* __restrict__ pre_b, const float4* __restrict__ WT_f,
     const float4* __restrict__ WT_b, const int* __restrict__ lengths,
     const float* __restrict__ outW,
     float* __restrict__ logits_f, float* __restrict__ logits_b,
     float* __restrict__ st_h, float* __restrict__ st_c,
     int t0, int CH){
  int dir = blockIdx.x & 1;
  int b = blockIdx.x >> 1;
  int len = lengths[b];
  const float4* pre = (dir ? pre_b : pre_f) + (size_t)b*CH*256;
  const float4* WT = dir ? WT_b : WT_f;
  float* lg = (dir ? logits_b : logits_f) + (size_t)b*512*9;
  __shared__ float h_lds[256];
  __shared__ float4 part[3*256];       // 12 KB
  __shared__ float oWs[2304];          // 9 KB
  __shared__ float4 wlds[4][NLD][256]; // 128 KB
  int tid = threadIdx.x;
  int j = tid & 255, q = tid >> 8;
  for (int i = tid; i < 2304; i += 1024) oWs[i] = outW[dir*2304 + i];
  for (int i = tid; i < 4*NLD*256; i += 1024){
    int qq = i >> 11;                 // / (NLD*256) with NLD=8
    int rr = i & (NLD*256 - 1);
    int dl = rr >> 8, jj = rr & 255;
    wlds[qq][dl][jj] = WT[(size_t)(qq*64 + NRD + dl)*256 + jj];
  }
  const float4* WTq = WT + (size_t)q*64*256;
  float4 wreg[NRD];
#pragma unroll
  for (int r=0; r<NRD; ++r) wreg[r] = WTq[(size_t)r*256 + j];
  float c = 0.f;
  if (t0 == 0){
    if (tid < 256) h_lds[tid] = 0.f;
  } else {
    if (tid < 256) h_lds[tid] = st_h[(dir*64+b)*256 + tid];
    if (q == 0) c = st_c[(dir*64+b)*256 + j];
  }
  __syncthreads();
  int tend = len < t0+CH ? len : t0+CH;
  const float4* WTs = WTq + (size_t)(NRD+NLD)*256 + j;
  const float* hR = h_lds + q*64;
  const float* hL = hR + NRD;
  const float* hS = hR + NRD + NLD;
  for (int t=t0; t<tend; ++t){
    int p = dir ? (len-1-t) : t;
    float4 acc = make_float4(0.f,0.f,0.f,0.f);
    // streamed rows (L2)
#pragma unroll 8
    for (int s=0; s<NSTREAM; ++s){
      float hv = hS[s];
      float4 w = WTs[(size_t)s*256];
      acc.x += w.x*hv; acc.y += w.y*hv; acc.z += w.z*hv; acc.w += w.w*hv;
    }
    // register-cached rows
#pragma unroll
    for (int r=0; r<NRD; ++r){
      float hv = hR[r];
      float4 w = wreg[r];
      acc.x += w.x*hv; acc.y += w.y*hv; acc.z += w.z*hv; acc.w += w.w*hv;
    }
    // LDS-cached rows
#pragma unroll
    for (int l=0; l<NLD; ++l){
      float hv = hL[l];
      float4 w = wlds[q][l][j];
      acc.x += w.x*hv; acc.y += w.y*hv; acc.z += w.z*hv; acc.w += w.w*hv;
    }
    __syncthreads();                    // all h_lds reads done
    if (q) part[(q-1)*256 + j] = acc;
    __syncthreads();
    if (q == 0){
      float4 p0 = pre[(size_t)(t - t0)*256 + j];
      float4 p1 = part[j], p2 = part[256+j], p3 = part[512+j];
      float gi = acc.x + p0.x + p1.x + p2.x + p3.x;
      float gf = acc.y + p0.y + p1.y + p2.y + p3.y;
      float gg = acc.z + p0.z + p1.z + p2.z + p3.z;
      float go = acc.w + p0.w + p1.w + p2.w + p3.w;
      c = sigf(gf)*c + sigf(gi)*tanhf(gg);
      float h = sigf(go)*tanhf(c);
      h_lds[j] = h;
    }
    __syncthreads();                    // h ready
    // logits contribution: 9 tags x 64 lanes
    if (tid < 576){
      int k = tid >> 6, l = tid & 63;
      float s = h_lds[l]*oWs[l*9+k] + h_lds[l+64]*oWs[(l+64)*9+k]
              + h_lds[l+128]*oWs[(l+128)*9+k] + h_lds[l+192]*oWs[(l+192)*9+k];
#pragma unroll
      for (int o=32; o; o>>=1) s += __shfl_down(s, o, 64);
      if (l == 0) lg[p*9 + k] = s;
    }
  }
  if (tid < 256) st_h[(dir*64+b)*256 + tid] = h_lds[tid];
  if (q == 0) st_c[(dir*64+b)*256 + j] = c;
}

// ---------------- merged CRF forward + Viterbi ----------------
__global__ __launch_bounds__(64) void crf_viterbi_kernel(const float* __restrict__ logits_f,
     const float* __restrict__ logits_b, const float* __restrict__ outb_,
     const int* __restrict__ tags, const int* __restrict__ lengths,
     const float* __restrict__ trans, const float* __restrict__ start_trans,
     const float* __restrict__ end_trans, float* __restrict__ loss_partial,
     float* __restrict__ preds){
  int wid = blockIdx.x;
  int is_crf = wid < 64 ? 1 : 0;
  int b = is_crf ? wid : wid - 64;
  int len = lengths[b];
  int tid = threadIdx.x;
  __shared__ float e_s[4608];
  __shared__ float tr[81];
  __shared__ float alpha[9];
  __shared__ int tg[512];
  __shared__ unsigned char bp[4608];
  const float* lf = logits_f + (size_t)b*4608;
  const float* lb = logits_b + (size_t)b*4608;
  for (int i=tid; i<4608; i+=64){
    int k = i - (i/9)*9;
    e_s[i] = lf[i] + lb[i] + outb_[k];
  }
  for (int i=tid; i<81; i+=64) tr[i] = trans[i];
  if (is_crf){
    for (int i=tid; i<512; i+=64) tg[i] = tags[b*512 + i];
    __syncthreads();
    if (tid < 9) alpha[tid] = start_trans[tid] + e_s[tid];
    __syncthreads();
    for (int t=1; t<len; ++t){
      float nxt = 0.f;
      if (tid < 9){
        float v[9];
#pragma unroll
        for (int j2=0;j2<9;j2++) v[j2] = alpha[j2] + tr[j2*9+tid];
        float m = v[0];
#pragma unroll
        for (int j2=1;j2<9;j2++) m = fmaxf(m, v[j2]);
        float ssum = 0.f;
#pragma unroll
        for (int j2=0;j2<9;j2++) ssum += expf(v[j2]-m);
        nxt = m + logf(ssum) + e_s[t*9+tid];
      }
      __syncthreads();
      if (tid < 9) alpha[tid] = nxt;
      __syncthreads();
    }
    if (tid == 0){
      float m = alpha[0] + end_trans[0];
      for (int k2=1;k2<9;k2++) m = fmaxf(m, alpha[k2]+end_trans[k2]);
      float ssum = 0.f;
      for (int k2=0;k2<9;k2++) ssum += expf(alpha[k2]+end_trans[k2]-m);
      float Z = m + logf(ssum);
      int prev = tg[0];
      float sc = start_trans[prev] + e_s[prev];
      for (int t=1;t<len;++t){
        int cur = tg[t];
        sc += tr[prev*9+cur] + e_s[t*9+cur];
        prev = cur;
      }
      sc += end_trans[prev];
      loss_partial[b] = Z - sc;
    }
  } else {
    __syncthreads();
    if (tid < 9) alpha[tid] = start_trans[tid] + e_s[tid];
    __syncthreads();
    for (int t=1; t<len; ++t){
      float nxt = 0.f; int bj = 0;
      if (tid < 9){
        float m = alpha[0] + tr[tid];
#pragma unroll
        for (int j2=1;j2<9;j2++){
          float v = alpha[j2] + tr[j2*9+tid];
          if (v > m){ m = v; bj = j2; }
        }
        nxt = m + e_s[t*9+tid];
      }
      __syncthreads();
      if (tid < 9){ alpha[tid] = nxt; bp[t*9+tid] = (unsigned char)bj; }
      __syncthreads();
    }
    for (int p2 = len + tid; p2 < 512; p2 += 64) preds[(size_t)b*512 + p2] = 0.f;
    if (tid == 0){
      float m = alpha[0] + end_trans[0]; int last = 0;
      for (int k2=1;k2<9;k2++){
        float v = alpha[k2] + end_trans[k2];
        if (v > m){ m = v; last = k2; }
      }
      int cur = last;
      preds[(size_t)b*512 + (len-1)] = (float)cur;
      for (int p2 = len-2; p2 >= 0; --p2){
        cur = bp[(p2+1)*9 + cur];
        preds[(size_t)b*512 + p2] = (float)cur;
      }
    }
  }
}

// ---------------- loss reduction ----------------
__global__ void loss_sum_kernel(const float* __restrict__ lp, float* __restrict__ out){
  float v = lp[threadIdx.x];
#pragma unroll
  for (int o=32; o; o>>=1) v += __shfl_down(v, o, 64);
  if (threadIdx.x == 0) out[0] = v;
}

extern "C" void kernel_launch(void* const* d_in, const int* in_sizes, int n_in,
                              void* d_out, int out_size, void* d_ws, size_t ws_size,
                              hipStream_t stream) {
  const float* word_embs  = (const float*)d_in[0];
  const int*   chars      = (const int*)  d_in[1];
  const int*   lengths    = (const int*)  d_in[2];
  const int*   tags       = (const int*)  d_in[3];
  const float* fin_W      = (const float*)d_in[4];
  const float* fin_b      = (const float*)d_in[5];
  const float* char_emb   = (const float*)d_in[6];
  const float* conv_W     = (const float*)d_in[7];
  const float* conv_b     = (const float*)d_in[8];
  const float* Wih_f      = (const float*)d_in[9];
  const float* Whh_f      = (const float*)d_in[10];
  const float* b_f        = (const float*)d_in[11];
  const float* Wih_b      = (const float*)d_in[12];
  const float* Whh_b      = (const float*)d_in[13];
  const float* b_b        = (const float*)d_in[14];
  const float* out_W      = (const float*)d_in[15];
  const float* out_b      = (const float*)d_in[16];
  const float* trans      = (const float*)d_in[17];
  const float* start_tr   = (const float*)d_in[18];
  const float* end_tr     = (const float*)d_in[19];

  float* ws = (float*)d_ws;
  // fixed layout (floats); all offsets multiple of 64 -> float4-aligned
  float*  x         = ws;                        // 13,107,200
  float4* Wp_f      = (float4*)(ws + 13107200);  //    409,600 floats
  float4* Wp_b      = (float4*)(ws + 13516800);  //    409,600
  float4* WT_f      = (float4*)(ws + 13926400);  //    262,144
  float4* WT_b      = (float4*)(ws + 14188544);  //    262,144
  float*  finWT     = ws + 14450688;             //     91,200 (300*304)
  float*  logits_f  = ws + 14541888;             //    294,912
  float*  logits_b  = ws + 14836800;             //    294,912
  float*  st_h      = ws + 15131712;             //     32,768
  float*  st_c      = ws + 15164480;             //     32,768
  float*  loss_part = ws + 15197248;             //         64
  const size_t FIXED_F = 15197312;               // floats used so far
  // choose largest time-chunk CH whose pre buffers fit ws_size
  int CH = 16, log2CH = 4;
  {
    const int cands[5]  = {512,256,128,64,32};
    const int lgs[5]    = {9,8,7,6,5};
    for (int i=0;i<5;i++){
      size_t need = (FIXED_F + (size_t)131072*cands[i]) * 4;
      if (need <= ws_size){ CH = cands[i]; log2CH = lgs[i]; break; }
    }
  }
  float4* pre_f = (float4*)(ws + FIXED_F);
  float4* pre_b = pre_f + (size_t)64*CH*256;     // 64*CH*1024 floats each

  float* out = (float*)d_out;

  pack_weights<<<1664, 256, 0, stream>>>(Wih_f, Wih_b, Whh_f, Whh_b, fin_W,
                                         Wp_f, Wp_b, WT_f, WT_b, finWT);
  embed_kernel<<<2048, 256, 0, stream>>>(word_embs, finWT, fin_b, x);
  char_kernel<<<4096, 256, 0, stream>>>(chars, char_emb, conv_W, conv_b, x);

  for (int t0 = 0; t0 < 512; t0 += CH){
    pre_gemm<<<dim3(CH, 4, 2), 256, 0, stream>>>(x, Wp_f, Wp_b, b_f, b_b, lengths,
                                                 pre_f, pre_b, t0, log2CH);
    lstm_scan<<<128, 1024, 0, stream>>>(pre_f, pre_b, WT_f, WT_b, lengths, out_W,
                                        logits_f, logits_b, st_h, st_c, t0, CH);
  }

  crf_viterbi_kernel<<<128, 64, 0, stream>>>(logits_f, logits_b, out_b, tags, lengths,
                                             trans, start_tr, end_tr, loss_part, out + 1);
  loss_sum_kernel<<<1, 64, 0, stream>>>(loss_part, out);
}